// Round 5
// baseline (2766.608 us; speedup 1.0000x reference)
//
#include <hip/hip_runtime.h>

#define TT 2048
#define NB 512

__device__ __forceinline__ float fsig(float x) {
    return 1.0f / (1.0f + __expf(-x));
}
__device__ __forceinline__ float ftanh(float x) {
    return 2.0f / (1.0f + __expf(-2.0f * x)) - 1.0f;
}

// DPP-move with 0-fill for invalid source lanes (bound_ctrl=1), VALU pipe.
template<int CTRL>
__device__ __forceinline__ float dpp0(float x) {
    return __int_as_float(
        __builtin_amdgcn_update_dpp(0, __float_as_int(x), CTRL, 0xF, 0xF, true));
}
// Full wave64 sum via DPP prefix idiom; result lands in lane 63.
__device__ __forceinline__ float wave_sum_dpp(float s) {
    s += dpp0<0x111>(s);   // row_shr:1
    s += dpp0<0x112>(s);   // row_shr:2
    s += dpp0<0x114>(s);   // row_shr:4
    s += dpp0<0x118>(s);   // row_shr:8  -> lane15/31/47/63 hold row sums
    s += dpp0<0x142>(s);   // row_bcast:15 -> lane31 = rows0+1, lane63 = rows2+3
    s += dpp0<0x143>(s);   // row_bcast:31 -> lane63 = total
    return s;
}

// Block = 5 waves. Waves 0-3: wave g owns gate g (TF order i,j,f,o), lane u =
// hidden unit u, 64 named-scalar W1 weights in VGPRs (R4: VGPR 88 confirmed
// resident). Wave 4: dedicated layer-2 scalar-chain wave, 2-step lagged off a
// 4-deep zp ring — its ~300 cyc/step runs concurrently, off the barrier path.
// z2 reduction: DPP row-reduce (VALU, ~60 cyc) replaces the 6x ds_bpermute
// butterfly (~780 cyc LDS-latency chain) — R1-R4's invariant serial wall.
// ONE __syncthreads per iteration in both branches (barrier counts match).
__global__ __launch_bounds__(320)
__attribute__((amdgpu_waves_per_eu(3, 3)))
void lstm2_kernel(const float* __restrict__ x,
                  const float* __restrict__ W1,
                  const float* __restrict__ b1,
                  const float* __restrict__ W2,
                  const float* __restrict__ b2,
                  float* __restrict__ out)
{
    __shared__ __align__(16) float xall[TT];        // 8 KB input row
    __shared__ __align__(16) float h1b[4][64];      // per-wave private h1 bcast
    __shared__ __align__(16) float gbuf[2][4][64];  // parity-dbuf gate values
    __shared__ float zp[4][4];                      // layer-2 partial ring

    const int tid  = threadIdx.x;
    const int wave = tid >> 6;
    const int lane = tid & 63;
    const int b    = blockIdx.x;

    for (int i = tid; i < TT; i += 320) xall[i] = x[b * TT + i];

    float* __restrict__ outb = out + b * TT;

    if (wave < 4) {
        // ---- compute waves ----
        const int col = (wave << 6) + lane;   // W1 (65,256) row-major column

#define DECLW(q) \
        const float wx##q = W1[(4*(q)+1)*256 + col]; \
        const float wy##q = W1[(4*(q)+2)*256 + col]; \
        const float wz##q = W1[(4*(q)+3)*256 + col]; \
        const float ww##q = W1[(4*(q)+4)*256 + col];
        DECLW(0)  DECLW(1)  DECLW(2)  DECLW(3)
        DECLW(4)  DECLW(5)  DECLW(6)  DECLW(7)
        DECLW(8)  DECLW(9)  DECLW(10) DECLW(11)
        DECLW(12) DECLW(13) DECLW(14) DECLW(15)
#undef DECLW

        const float w0x  = W1[col];              // row 0 (x-part)
        const float bias = b1[col];
        const float w2g  = W2[lane * 4 + wave];  // W2 (65,4), h1-part column

        float c1 = 0.0f;                         // redundant per wave
        h1b[wave][lane] = 0.0f;
        __syncthreads();

        for (int it = 0; it <= TT + 1; ++it) {
            const int p = it & 1;
            // Phase A: gates(it) from h1(it-1) in own broadcast row
            if (it < TT) {
                const float* hr = h1b[wave];
                float a0 = fmaf(xall[it], w0x, bias);
                float a1 = 0.f, a2 = 0.f, a3 = 0.f;
#define FMA4(q) \
                a0 = fmaf(hr[4*(q)+0], wx##q, a0); \
                a1 = fmaf(hr[4*(q)+1], wy##q, a1); \
                a2 = fmaf(hr[4*(q)+2], wz##q, a2); \
                a3 = fmaf(hr[4*(q)+3], ww##q, a3);
                FMA4(0)  FMA4(1)  FMA4(2)  FMA4(3)
                FMA4(4)  FMA4(5)  FMA4(6)  FMA4(7)
                FMA4(8)  FMA4(9)  FMA4(10) FMA4(11)
                FMA4(12) FMA4(13) FMA4(14) FMA4(15)
#undef FMA4
                const float acc = (a0 + a1) + (a2 + a3);
                float v;
                if (wave == 1)      v = ftanh(acc);         // j
                else if (wave == 2) v = fsig(acc + 1.0f);   // f + forget bias
                else                v = fsig(acc);          // i, o
                gbuf[p][wave][lane] = v;
            }
            __syncthreads();   // the ONLY barrier per iteration
            // Phase B: combine gates -> c1, h1(it); DPP-reduce layer-2 partial
            if (it < TT) {
                const float gi = gbuf[p][0][lane];
                const float gj = gbuf[p][1][lane];
                const float gf = gbuf[p][2][lane];
                const float go = gbuf[p][3][lane];
                c1 = fmaf(c1, gf, gi * gj);
                const float h1 = ftanh(c1) * go;
                h1b[wave][lane] = h1;              // wave-private, no barrier
                const float s = wave_sum_dpp(h1 * w2g);  // VALU cross-lane
                if (lane == 63) zp[it & 3][wave] = s;    // ring slot for step it
            }
        }
    } else {
        // ---- layer-2 scalar-chain wave (wave 4) ----
        const float w2h0 = W2[256], w2h1 = W2[257], w2h2 = W2[258], w2h3 = W2[259];
        const float b20 = b2[0], b21 = b2[1], b22 = b2[2], b23 = b2[3];
        float c2 = 0.0f, h2 = 0.0f;
        __syncthreads();

        for (int it = 0; it <= TT + 1; ++it) {
            // consume step it-2: zp written in B(it-2), 2 barriers of slack
            if (it >= 2 && lane == 0) {
                const int q = (it - 2) & 3;
                const float zi = zp[q][0] + fmaf(h2, w2h0, b20);
                const float zj = zp[q][1] + fmaf(h2, w2h1, b21);
                const float zf = zp[q][2] + fmaf(h2, w2h2, b22);
                const float zo = zp[q][3] + fmaf(h2, w2h3, b23);
                c2 = c2 * fsig(zf + 1.0f) + fsig(zi) * ftanh(zj);
                h2 = ftanh(c2) * fsig(zo);
                outb[it - 2] = h2;
            }
            __syncthreads();
        }
    }
}

extern "C" void kernel_launch(void* const* d_in, const int* in_sizes, int n_in,
                              void* d_out, int out_size, void* d_ws, size_t ws_size,
                              hipStream_t stream)
{
    const float* x  = (const float*)d_in[0];
    const float* W1 = (const float*)d_in[1];
    const float* b1 = (const float*)d_in[2];
    const float* W2 = (const float*)d_in[3];
    const float* b2 = (const float*)d_in[4];
    float* out = (float*)d_out;
    lstm2_kernel<<<NB, 320, 0, stream>>>(x, W1, b1, W2, b2, out);
}

// Round 6
// 1637.740 us; speedup vs baseline: 1.6893x; 1.6893x over previous
//
#include <hip/hip_runtime.h>

#define TT 2048
#define NB 512

__device__ __forceinline__ float rcpf(float x) { return __builtin_amdgcn_rcpf(x); }
__device__ __forceinline__ float fsig(float x) { return rcpf(1.0f + __expf(-x)); }
__device__ __forceinline__ float ftanh(float x) {
    return fmaf(2.0f, rcpf(1.0f + __expf(-2.0f * x)), -1.0f);
}

// DPP move, bound_ctrl=1 (R5-verified path).
template<int CTRL>
__device__ __forceinline__ float dpp0(float x) {
    return __int_as_float(
        __builtin_amdgcn_update_dpp(0, __float_as_int(x), CTRL, 0xF, 0xF, true));
}
// Full wave64 sum; result in lane 63 (R5-verified).
__device__ __forceinline__ float wave_sum_dpp(float s) {
    s += dpp0<0x111>(s);   // row_shr:1
    s += dpp0<0x112>(s);   // row_shr:2
    s += dpp0<0x114>(s);   // row_shr:4
    s += dpp0<0x118>(s);   // row_shr:8
    s += dpp0<0x142>(s);   // row_bcast:15
    s += dpp0<0x143>(s);   // row_bcast:31
    return s;
}
// Broadcast lane (quad_base+Q) to all 4 lanes of the quad: ctrl = Q*0x55.
template<int Q>
__device__ __forceinline__ float qbcast(float x) {
    return __int_as_float(
        __builtin_amdgcn_update_dpp(0, __float_as_int(x), Q * 0x55, 0xF, 0xF, true));
}

// Block = 4 waves, 1 block per batch element. QUAD-GATE layout: lane = 4*u'+g,
// wave w owns units 16w..16w+15; each quad holds all 4 gates (i,j,f,o) of one
// unit, so the gate combine is 4 quad_perm DPP broadcasts — no LDS, no barrier.
// Only h1 (16 floats/wave) crosses waves via a parity-dbuf 64-float row:
// ONE __syncthreads/step draining lgkm ONLY. h2 output is buffered in an LDS
// ring and flushed as one coalesced 64-float store every 64 steps (after the
// barrier) — removing the per-step vmcnt(0) store-drain that sat on every
// barrier in R1-R5. Layer-2: DPP wave-sum partials (1-lag), scalar chain on
// wave3/lane0 (2-lag), both ring-buffered.
__global__ __launch_bounds__(256)
__attribute__((amdgpu_waves_per_eu(2, 2)))
void lstm2_kernel(const float* __restrict__ x,
                  const float* __restrict__ W1,
                  const float* __restrict__ b1,
                  const float* __restrict__ W2,
                  const float* __restrict__ b2,
                  float* __restrict__ out)
{
    __shared__ __align__(16) float xall[TT];       // 8 KB input row
    __shared__ __align__(16) float h1row[2][64];   // parity-dbuf h1 broadcast
    __shared__ __align__(16) float zp[4][4];       // layer-2 partial ring
    __shared__ __align__(16) float h2buf[2][64];   // h2 output staging ring

    const int tid  = threadIdx.x;
    const int wave = tid >> 6;
    const int lane = tid & 63;
    const int b    = blockIdx.x;

    for (int i = tid; i < TT; i += 256) xall[i] = x[b * TT + i];

    const int g    = lane & 3;          // gate (i,j,f,o)
    const int u    = lane >> 2;         // local unit 0..15
    const int unit = (wave << 4) + u;   // global unit 0..63
    const int col  = (g << 6) + unit;   // W1 (65,256) column

#define DECLW(q) \
    const float wx##q = W1[(4*(q)+1)*256 + col]; \
    const float wy##q = W1[(4*(q)+2)*256 + col]; \
    const float wz##q = W1[(4*(q)+3)*256 + col]; \
    const float ww##q = W1[(4*(q)+4)*256 + col];
    DECLW(0)  DECLW(1)  DECLW(2)  DECLW(3)
    DECLW(4)  DECLW(5)  DECLW(6)  DECLW(7)
    DECLW(8)  DECLW(9)  DECLW(10) DECLW(11)
    DECLW(12) DECLW(13) DECLW(14) DECLW(15)
#undef DECLW

    const float w0x  = W1[col];              // row 0 (x-part)
    const float bias = b1[col];
    const float w2g  = W2[lane * 4 + wave];  // layer-2 h1-part, gate = wave

    // layer-2 scalar-chain constants (uniform scalar loads)
    const float w2h0 = W2[256], w2h1 = W2[257], w2h2 = W2[258], w2h3 = W2[259];
    const float b20 = b2[0], b21 = b2[1], b22 = b2[2], b23 = b2[3];

    float c1 = 0.0f;                     // redundant per quad
    float c2 = 0.0f, h2 = 0.0f;          // layer-2 state (wave3/lane0)

    if (tid < 64) h1row[0][tid] = 0.0f;
    __syncthreads();

    float* __restrict__ outb = out + b * TT;

    for (int it = 0; it <= TT + 2; ++it) {
        const int p = it & 1;
        // ---- Phase A: gates(it) from h1(it-1) = h1row[p]; combine in-quad.
        if (it < TT) {
            const float* hr = h1row[p];
            float a0 = fmaf(xall[it], w0x, bias);
            float a1 = 0.f, a2 = 0.f, a3 = 0.f;
#define FMA4(q) \
            a0 = fmaf(hr[4*(q)+0], wx##q, a0); \
            a1 = fmaf(hr[4*(q)+1], wy##q, a1); \
            a2 = fmaf(hr[4*(q)+2], wz##q, a2); \
            a3 = fmaf(hr[4*(q)+3], ww##q, a3);
            FMA4(0)  FMA4(1)  FMA4(2)  FMA4(3)
            FMA4(4)  FMA4(5)  FMA4(6)  FMA4(7)
            FMA4(8)  FMA4(9)  FMA4(10) FMA4(11)
            FMA4(12) FMA4(13) FMA4(14) FMA4(15)
#undef FMA4
            const float acc = (a0 + a1) + (a2 + a3);
            // branchless dual nonlin + select (avoids 4-way quad divergence)
            const float zadj = acc + ((g == 2) ? 1.0f : 0.0f);  // forget bias
            const float es   = __expf(-zadj);
            const float sg   = rcpf(1.0f + es);                 // sigmoid
            const float th   = fmaf(2.0f, rcpf(1.0f + es * es), -1.0f); // tanh
            const float v    = (g == 1) ? th : sg;
            // quad gate exchange: pure VALU, no LDS, no barrier
            const float gi = qbcast<0>(v);
            const float gj = qbcast<1>(v);
            const float gf = qbcast<2>(v);
            const float go = qbcast<3>(v);
            c1 = fmaf(c1, gf, gi * gj);
            const float h1 = ftanh(c1) * go;
            if (g == 0) h1row[p ^ 1][unit] = h1;   // 16 floats/wave
        }
        // ---- layer-2 partial for step it-1 from h1row[p] (all lanes active)
        if (it >= 1 && it <= TT) {
            const float hs = h1row[p][lane];
            const float s  = wave_sum_dpp(hs * w2g);
            if (lane == 63) zp[(it - 1) & 3][wave] = s;
        }
        // ---- scalar chain for step it-2 (zp crossed last barrier)
        if (wave == 3 && lane == 0 && it >= 2 && it <= TT + 1) {
            const int st = it - 2;
            const float4 z4 = *(const float4*)zp[st & 3];
            const float zi = z4.x + fmaf(h2, w2h0, b20);
            const float zj = z4.y + fmaf(h2, w2h1, b21);
            const float zf = z4.z + fmaf(h2, w2h2, b22);
            const float zo = z4.w + fmaf(h2, w2h3, b23);
            c2 = c2 * fsig(zf + 1.0f) + fsig(zi) * ftanh(zj);
            h2 = ftanh(c2) * fsig(zo);
            h2buf[(st >> 6) & 1][st & 63] = h2;    // LDS staging, no global
        }
        __syncthreads();   // the ONLY barrier; drains lgkm only
        // ---- batched output flush: 1 coalesced store per 64 steps (wave1),
        //      issued AFTER the barrier so the vmcnt ack hides under the next
        //      full iteration of work.
        if (wave == 1 && it >= 66 && (it & 63) == 2) {
            const int blk = (it - 66) >> 6;        // 0..31
            outb[(blk << 6) + lane] = h2buf[blk & 1][lane];
        }
    }
}

extern "C" void kernel_launch(void* const* d_in, const int* in_sizes, int n_in,
                              void* d_out, int out_size, void* d_ws, size_t ws_size,
                              hipStream_t stream)
{
    const float* x  = (const float*)d_in[0];
    const float* W1 = (const float*)d_in[1];
    const float* b1 = (const float*)d_in[2];
    const float* W2 = (const float*)d_in[3];
    const float* b2 = (const float*)d_in[4];
    float* out = (float*)d_out;
    lstm2_kernel<<<NB, 256, 0, stream>>>(x, W1, b1, W2, b2, out);
}